// Round 16
// baseline (179.451 us; speedup 1.0000x reference)
//
#include <hip/hip_runtime.h>
#include <math.h>

#define CCH 96
#define HH 112
#define WW 112
#define HWSZ 12544      // 112*112
#define NB 32
#define PIX 64
#define NBLK 196        // tiles per image (14x14 for k_mid, 1D-64 for others)
#define EPSV 1e-5f
#define APITCH 120      // bf16 elems per A-row in conv1 staging LDS
#define TP2 104         // u16 pitch of [pixel][channel] transpose buffer (52 dw, 2-way)
#define TPITCHF 68      // f32 transpose pitch in k_out
#define ROWC 96         // channels per pixel-major row
#define HPITCH 104      // bf16 elems per halo row in k_mid LDS

typedef __attribute__((ext_vector_type(8))) short bf16x8;
typedef __attribute__((ext_vector_type(4))) float f32x4;
typedef __attribute__((ext_vector_type(8))) unsigned short u16x8;

__device__ __forceinline__ unsigned short f2bf(float f) {
    union { float f; unsigned u; } v; v.f = f;
    unsigned r = v.u + 0x7fffu + ((v.u >> 16) & 1u);   // RTNE
    return (unsigned short)(r >> 16);
}
__device__ __forceinline__ float bf2f(unsigned short h) {
    union { unsigned u; float f; } v; v.u = ((unsigned)h) << 16;
    return v.f;
}
__device__ __forceinline__ unsigned cvt_pk_bf16(float lo, float hi) {
    unsigned r;
    asm("v_cvt_pk_bf16_f32 %0, %1, %2" : "=v"(r) : "v"(lo), "v"(hi));
    return r;
}
// tanh-form GELU via hw exp2/rcp (validated rounds 5-14)
__device__ __forceinline__ float gelu_f(float x) {
    const float K = 2.3022082f;
    float u = x * x;
    float p = x * fmaf(0.044715f, u, 1.0f);
    float e = __builtin_amdgcn_exp2f(p * K);
    float r = __builtin_amdgcn_rcpf(e + 1.0f);
    return x - x * r;
}

__device__ __forceinline__ void block_reduce_write(float sum, float sumsq,
                                                   float* part, int slot) {
    #pragma unroll
    for (int off = 32; off > 0; off >>= 1) {
        sum += __shfl_down(sum, off);
        sumsq += __shfl_down(sumsq, off);
    }
    __shared__ float ls[8];
    const int wid = threadIdx.x >> 6, lane = threadIdx.x & 63;
    if (lane == 0) { ls[wid] = sum; ls[4 + wid] = sumsq; }
    __syncthreads();
    if (threadIdx.x == 0) {
        part[slot * 2 + 0] = ls[0] + ls[1] + ls[2] + ls[3];
        part[slot * 2 + 1] = ls[4] + ls[5] + ls[6] + ls[7];
    }
}

// wave-0 reduce of one sample's 196 partial pairs -> (mu, inv) in shared
__device__ __forceinline__ void stats_reduce(const float* __restrict__ part,
                                             int b, float* sh_mu, float* sh_inv) {
    const int t = threadIdx.x;
    if (t < 64) {
        float s = 0.f, q = 0.f;
        for (int i = t; i < NBLK; i += 64) {
            s += part[(b * NBLK + i) * 2 + 0];
            q += part[(b * NBLK + i) * 2 + 1];
        }
        #pragma unroll
        for (int off = 32; off > 0; off >>= 1) {
            s += __shfl_down(s, off);
            q += __shfl_down(q, off);
        }
        if (t == 0) {
            const float n = (float)CCH * (float)HWSZ;
            const float mu = s / n;
            const float var = q / n - mu * mu;
            *sh_mu = mu;
            *sh_inv = rsqrtf(var + EPSV);
        }
    }
}

// write one C-fragment column (4 pixels x 1 ch) into [pixel][ch] LDS, conflict-free
__device__ __forceinline__ void frag_to_lds_t(unsigned short* Tsd2, int p0, int o,
                                              const f32x4 v) {
    const unsigned lo = cvt_pk_bf16(v[0], v[1]);
    const unsigned hi = cvt_pk_bf16(v[2], v[3]);
    Tsd2[(p0 + 0) * TP2 + o] = (unsigned short)lo;
    Tsd2[(p0 + 1) * TP2 + o] = (unsigned short)(lo >> 16);
    Tsd2[(p0 + 2) * TP2 + o] = (unsigned short)hi;
    Tsd2[(p0 + 3) * TP2 + o] = (unsigned short)(hi >> 16);
}

// ---- weight prep: fp32 [O][C] -> bf16 fragment layout [m][n0][k0][lane][8] ----
__global__ void k_prep(const float* __restrict__ w1, const float* __restrict__ w21,
                       const float* __restrict__ w22,
                       unsigned short* __restrict__ Bp) {
    const int t = blockIdx.x * 256 + threadIdx.x;   // 3*18*512 = 27648
    if (t >= 3 * 18 * 512) return;
    const int j  = t & 7;
    const int l  = (t >> 3) & 63;
    const int s  = t >> 9;
    const int k0 = s % 3;
    const int n0 = (s / 3) % 6;
    const int m  = s / 18;
    const float* w = (m == 0) ? w1 : (m == 1) ? w21 : w22;
    const int n = n0 * 16 + (l & 15);
    const int k = k0 * 32 + (l >> 4) * 8 + j;
    Bp[t] = f2bf(w[n * CCH + k]);
}

// ---- K1: conv1 (x fp32 channel-major -> h1 bf16 PIXEL-major) + GN1 partials
__global__ __launch_bounds__(256) void k_conv1(
        const float* __restrict__ x, const unsigned short* __restrict__ Bp,
        const float* __restrict__ b1, unsigned short* __restrict__ h1t,
        float* __restrict__ part) {
    __shared__ unsigned short Asd[64 * APITCH];    // 15360 B
    __shared__ unsigned short Tsd2[64 * TP2];      // 13312 B (separate: no overlay barrier)

    const int b = blockIdx.y;
    const int hw0 = blockIdx.x * PIX;
    const int wid = __builtin_amdgcn_readfirstlane(threadIdx.x >> 6);
    const int lane = threadIdx.x & 63;

    const float* xb = x + (size_t)b * CCH * HWSZ + hw0;
    #pragma unroll
    for (int i = 0; i < 24; i += 2) {
        const int c = wid * 24 + i;
        *(unsigned*)&Asd[lane * APITCH + c] =
            cvt_pk_bf16(xb[(size_t)c * HWSZ + lane], xb[(size_t)(c + 1) * HWSZ + lane]);
    }
    __syncthreads();

    bf16x8 a[3];
    const int arow = (wid * 16 + (lane & 15)) * APITCH;
    const int acol = (lane >> 4) * 8;
    #pragma unroll
    for (int k0 = 0; k0 < 3; ++k0)
        a[k0] = *(const bf16x8*)&Asd[arow + k0 * 32 + acol];
    // no barrier needed: Tsd2 is a separate buffer

    f32x4 acc[6];
    #pragma unroll
    for (int n0 = 0; n0 < 6; ++n0) {
        const float bias = b1[n0 * 16 + (lane & 15)];
        acc[n0] = (f32x4){bias, bias, bias, bias};
        #pragma unroll
        for (int k0 = 0; k0 < 3; ++k0) {
            const bf16x8 bf = *(const bf16x8*)(Bp + (n0 * 3 + k0) * 512 + lane * 8);
            acc[n0] = __builtin_amdgcn_mfma_f32_16x16x32_bf16(a[k0], bf, acc[n0], 0, 0, 0);
        }
    }

    float sum = 0.f, sumsq = 0.f;
    const int p0 = wid * 16 + (lane >> 4) * 4;
    #pragma unroll
    for (int n0 = 0; n0 < 6; ++n0) {
        const int o = n0 * 16 + (lane & 15);
        #pragma unroll
        for (int r = 0; r < 4; ++r) {
            const float v = acc[n0][r];
            sum += v; sumsq += v * v;
        }
        frag_to_lds_t(Tsd2, p0, o, acc[n0]);
    }
    __syncthreads();

    // cooperative PIXEL-major store (incremental div/mod: step 256 = 21*12 + 4)
    unsigned short* ob = h1t + ((size_t)b * HWSZ + hw0) * ROWC;
    {
        int pr = threadIdx.x / 12;
        int cc = threadIdx.x % 12;
        #pragma unroll
        for (int it = 0; it < 3; ++it) {
            const int c16 = cc * 8;
            *(uint4*)&ob[(size_t)pr * ROWC + c16] = *(const uint4*)&Tsd2[pr * TP2 + c16];
            pr += 21; cc += 4;
            if (cc >= 12) { cc -= 12; pr += 1; }
        }
    }
    block_reduce_write(sum, sumsq, part, b * NBLK + blockIdx.x);
}

// ---- K2: GN1 stats -> per-(b,c) scale/shift table (scale[c], shift[96+c]) ----
__global__ void k_scsh(const float* __restrict__ part,
                       const float* __restrict__ gw, const float* __restrict__ gb,
                       float* __restrict__ scsh) {
    const int b = blockIdx.x;
    __shared__ float sh_mu, sh_inv;
    stats_reduce(part, b, &sh_mu, &sh_inv);
    __syncthreads();
    const int t = threadIdx.x;   // 128
    if (t < CCH) {
        const float sc = sh_inv * gw[t];
        scsh[b * 2 * CCH + t] = sc;
        scsh[b * 2 * CCH + CCH + t] = gb[t] - sh_mu * sc;
    }
}

// ---- K3: fused gn1+gelu (halo-staged, T14 async-split, scsh-precomputed)
//      -> 2 GEMMs -> gelu+add -> h2t + GN2 partials. 8x8 tile, 10x10 halo.
__global__ __launch_bounds__(256) void k_mid(
        const unsigned short* __restrict__ h1t,
        const unsigned short* __restrict__ BpA, const unsigned short* __restrict__ BpB,
        const float* __restrict__ b21, const float* __restrict__ b22,
        const float* __restrict__ scsh,
        unsigned short* __restrict__ h2t, float* __restrict__ part2) {
    __shared__ unsigned short Hs[100 * HPITCH];    // 20800 B
    __shared__ unsigned short Tsd2[64 * TP2];      // 13312 B (separate: no overlay barrier)

    const int b = blockIdx.y;
    const int oy = (blockIdx.x / 14) * 8;          // tile origin
    const int ox = (blockIdx.x % 14) * 8;
    const int tid = threadIdx.x;

    // ---- T14 phase A: ISSUE halo global loads FIRST; latency overlaps the
    // scsh table loads below.
    const unsigned short* hb1 = h1t + (size_t)b * HWSZ * ROWC;
    u16x8 gv0, gv1, gv2, gv3, gv4;
    bool ok0 = false, ok1 = false, ok2 = false, ok3 = false, ok4 = false;
    int lr0 = 0, c0 = 0;
    if (tid < 240) {
        lr0 = tid / 12;                        // 0..19 (row within 20-row band)
        c0  = (tid % 12) * 8;                  // channel start
        const int a0  = (lr0 >= 10) ? 1 : 0;
        const int b0  = lr0 - 10 * a0;
        const int wwg = ox - 1 + b0;           // global col (iteration-invariant)
        const bool okw = (unsigned)wwg < WW;
        const int hh0 = oy - 1 + a0;
#define LOAD_IT(K, gvK, okK)                                                    \
        {                                                                       \
            const int hh = hh0 + 2 * (K);                                       \
            okK = okw && (unsigned)hh < HH;                                     \
            const size_t off = okK ? (((size_t)hh * WW + wwg) * ROWC + c0) : 0; \
            gvK = *(const u16x8*)&hb1[off];                                     \
        }
        LOAD_IT(0, gv0, ok0)
        LOAD_IT(1, gv1, ok1)
        LOAD_IT(2, gv2, ok2)
        LOAD_IT(3, gv3, ok3)
        LOAD_IT(4, gv4, ok4)
#undef LOAD_IT
    }

    // ---- phase B/C: load scale/shift (L2-resident) and gn1+gelu -> Hs
    if (tid < 240) {
        const float* scb = scsh + b * 2 * CCH;
        const f32x4 s0 = *(const f32x4*)&scb[c0];
        const f32x4 s1 = *(const f32x4*)&scb[c0 + 4];
        const f32x4 t0 = *(const f32x4*)&scb[CCH + c0];
        const f32x4 t1 = *(const f32x4*)&scb[CCH + c0 + 4];
#define PROC_IT(K, gvK, okK)                                                    \
        {                                                                       \
            unsigned r0 = 0, r1 = 0, r2 = 0, r3 = 0;                            \
            if (okK) {                                                          \
                float f0 = gelu_f(fmaf(bf2f(gvK[0]), s0[0], t0[0]));            \
                float f1 = gelu_f(fmaf(bf2f(gvK[1]), s0[1], t0[1]));            \
                float f2 = gelu_f(fmaf(bf2f(gvK[2]), s0[2], t0[2]));            \
                float f3 = gelu_f(fmaf(bf2f(gvK[3]), s0[3], t0[3]));            \
                float f4 = gelu_f(fmaf(bf2f(gvK[4]), s1[0], t1[0]));            \
                float f5 = gelu_f(fmaf(bf2f(gvK[5]), s1[1], t1[1]));            \
                float f6 = gelu_f(fmaf(bf2f(gvK[6]), s1[2], t1[2]));            \
                float f7 = gelu_f(fmaf(bf2f(gvK[7]), s1[3], t1[3]));            \
                r0 = cvt_pk_bf16(f0, f1);                                       \
                r1 = cvt_pk_bf16(f2, f3);                                       \
                r2 = cvt_pk_bf16(f4, f5);                                       \
                r3 = cvt_pk_bf16(f6, f7);                                       \
            }                                                                   \
            *(uint4*)&Hs[((K) * 20 + lr0) * HPITCH + c0] =                      \
                make_uint4(r0, r1, r2, r3);                                     \
        }
        PROC_IT(0, gv0, ok0)
        PROC_IT(1, gv1, ok1)
        PROC_IT(2, gv2, ok2)
        PROC_IT(3, gv3, ok3)
        PROC_IT(4, gv4, ok4)
#undef PROC_IT
    }
    __syncthreads();

    const int wid = __builtin_amdgcn_readfirstlane(tid >> 6);
    const int lane = tid & 63;
    const int p = wid * 16 + (lane & 15);          // tile-local pixel 0..63
    const int hr = ((p >> 3) + 1) * 10 + (p & 7) + 1;   // center halo row
    const int acol8 = (lane >> 4) * 8;

    // chunk k0=0: shift +1; k0=1: center; k0=2: shift -1 (all in-LDS, pre-zeroed)
    bf16x8 alr[3], atd[3];
    alr[0] = *(const bf16x8*)&Hs[(hr + 1)  * HPITCH +  0 + acol8];
    alr[1] = *(const bf16x8*)&Hs[hr        * HPITCH + 32 + acol8];
    alr[2] = *(const bf16x8*)&Hs[(hr - 1)  * HPITCH + 64 + acol8];
    atd[0] = *(const bf16x8*)&Hs[(hr + 10) * HPITCH +  0 + acol8];
    atd[1] = alr[1];
    atd[2] = *(const bf16x8*)&Hs[(hr - 10) * HPITCH + 64 + acol8];

    f32x4 accA[6], accB[6];
    #pragma unroll
    for (int n0 = 0; n0 < 6; ++n0) {
        const float biasA = b21[n0 * 16 + (lane & 15)];
        const float biasB = b22[n0 * 16 + (lane & 15)];
        accA[n0] = (f32x4){biasA, biasA, biasA, biasA};
        accB[n0] = (f32x4){biasB, biasB, biasB, biasB};
        #pragma unroll
        for (int k0 = 0; k0 < 3; ++k0) {
            const bf16x8 bA = *(const bf16x8*)(BpA + (n0 * 3 + k0) * 512 + lane * 8);
            const bf16x8 bB = *(const bf16x8*)(BpB + (n0 * 3 + k0) * 512 + lane * 8);
            accA[n0] = __builtin_amdgcn_mfma_f32_16x16x32_bf16(alr[k0], bA, accA[n0], 0, 0, 0);
            accB[n0] = __builtin_amdgcn_mfma_f32_16x16x32_bf16(atd[k0], bB, accB[n0], 0, 0, 0);
        }
    }
    // no barrier needed: Tsd2 is a separate buffer

    float sum = 0.f, sumsq = 0.f;
    const int p0 = wid * 16 + (lane >> 4) * 4;
    #pragma unroll
    for (int n0 = 0; n0 < 6; ++n0) {
        const int o = n0 * 16 + (lane & 15);
        f32x4 vv;
        #pragma unroll
        for (int r = 0; r < 4; ++r) {
            const float v = gelu_f(accA[n0][r]) + gelu_f(accB[n0][r]);
            sum += v; sumsq += v * v;
            vv[r] = v;
        }
        frag_to_lds_t(Tsd2, p0, o, vv);
    }
    __syncthreads();

    unsigned short* ob = h2t + (size_t)b * HWSZ * ROWC;
    {
        int pr = tid / 12;
        int cc = tid % 12;
        #pragma unroll
        for (int it = 0; it < 3; ++it) {
            const int c16 = cc * 8;
            const size_t gp = (size_t)(oy + (pr >> 3)) * WW + ox + (pr & 7);
            *(uint4*)&ob[gp * ROWC + c16] = *(const uint4*)&Tsd2[pr * TP2 + c16];
            pr += 21; cc += 4;
            if (cc >= 12) { cc -= 12; pr += 1; }
        }
    }
    block_reduce_write(sum, sumsq, part2, b * NBLK + blockIdx.x);
}

// ---- K4: per-sample GN2 fold into conv3 (stats folded in) ----
__global__ void k_wprep(const float* __restrict__ w3, const float* __restrict__ b3,
                        const float* __restrict__ part2,
                        const float* __restrict__ gw, const float* __restrict__ gb,
                        unsigned short* __restrict__ W3p, float* __restrict__ biasp) {
    const int b = blockIdx.x;
    __shared__ float ts[CCH], th[CCH];
    __shared__ float sh_mu, sh_inv;
    stats_reduce(part2, b, &sh_mu, &sh_inv);
    __syncthreads();
    const int t = threadIdx.x;
    if (t < CCH) {
        const float sc = sh_inv * gw[t];
        ts[t] = sc;
        th[t] = gb[t] - sh_mu * sc;
    }
    __syncthreads();
    unsigned short* Wb = W3p + b * 9216;
    #pragma unroll
    for (int i = 0; i < 36; ++i) {
        const int idx = t + i * 256;               // < 9216
        const int j = idx & 7;
        const int l = (idx >> 3) & 63;
        const int s = idx >> 9;
        const int k0 = s % 3, n0 = s / 3;
        const int n = n0 * 16 + (l & 15);
        const int k = k0 * 32 + (l >> 4) * 8 + j;
        Wb[idx] = f2bf(w3[n * CCH + k] * ts[k]);
    }
    if (t < CCH) {
        float a = b3[t];
        for (int c = 0; c < CCH; ++c) a = fmaf(w3[t * CCH + c], th[c], a);
        biasp[b * CCH + t] = a;
    }
}

// ---- K5: raw frag loads from h2t -> conv3' -> out fp32 channel-major ----
__global__ __launch_bounds__(256) void k_out(
        const unsigned short* __restrict__ h2t, const unsigned short* __restrict__ W3p,
        const float* __restrict__ biasp, float* __restrict__ out) {
    __shared__ float Tf[CCH * TPITCHF];   // 26112 B

    const int b = blockIdx.y;
    const int hw0 = blockIdx.x * PIX;
    const int wid = __builtin_amdgcn_readfirstlane(threadIdx.x >> 6);
    const int lane = threadIdx.x & 63;
    const int prow = hw0 + wid * 16 + (lane & 15);
    const int acol8 = (lane >> 4) * 8;

    const unsigned short* hb = h2t + (size_t)b * HWSZ * ROWC;
    bf16x8 a[3];
    #pragma unroll
    for (int k0 = 0; k0 < 3; ++k0)
        a[k0] = *(const bf16x8*)(hb + (size_t)prow * ROWC + k0 * 32 + acol8);

    const unsigned short* Bb = W3p + b * 9216;
    f32x4 acc[6];
    #pragma unroll
    for (int n0 = 0; n0 < 6; ++n0) {
        const float bias = biasp[b * CCH + n0 * 16 + (lane & 15)];
        acc[n0] = (f32x4){bias, bias, bias, bias};
        #pragma unroll
        for (int k0 = 0; k0 < 3; ++k0) {
            const bf16x8 bf = *(const bf16x8*)(Bb + (n0 * 3 + k0) * 512 + lane * 8);
            acc[n0] = __builtin_amdgcn_mfma_f32_16x16x32_bf16(a[k0], bf, acc[n0], 0, 0, 0);
        }
    }

    const int p0 = wid * 16 + (lane >> 4) * 4;
    #pragma unroll
    for (int n0 = 0; n0 < 6; ++n0) {
        const int o = n0 * 16 + (lane & 15);
        *(f32x4*)&Tf[o * TPITCHF + p0] = acc[n0];
    }
    __syncthreads();

    float* op = out + (size_t)b * CCH * HWSZ + hw0;
    #pragma unroll
    for (int it = 0; it < 6; ++it) {
        const int o = it * 16 + (threadIdx.x >> 4);
        const int p = (threadIdx.x & 15) * 4;
        *(f32x4*)&op[(size_t)o * HWSZ + p] = *(const f32x4*)&Tf[o * TPITCHF + p];
    }
}

extern "C" void kernel_launch(void* const* d_in, const int* in_sizes, int n_in,
                              void* d_out, int out_size, void* d_ws, size_t ws_size,
                              hipStream_t stream) {
    const float* x    = (const float*)d_in[0];
    const float* w1   = (const float*)d_in[1];
    const float* b1   = (const float*)d_in[2];
    const float* w21  = (const float*)d_in[3];
    const float* b21  = (const float*)d_in[4];
    const float* w22  = (const float*)d_in[5];
    const float* b22  = (const float*)d_in[6];
    const float* w3   = (const float*)d_in[7];
    const float* b3   = (const float*)d_in[8];
    const float* gn1w = (const float*)d_in[9];
    const float* gn1b = (const float*)d_in[10];
    const float* gn2w = (const float*)d_in[11];
    const float* gn2b = (const float*)d_in[12];

    // Workspace layout — verified non-overlapping (R4 lesson):
    //   Bp    [0,       55296)
    //   part1 [73728,   123904)
    //   part2 [123904,  174080)
    //   scsh1 [176128,  200704)
    //   W3p   [200704,  790528)
    //   biasp [790528,  802816)
    //   h2t   [1048576, +77 MB)
    char* base = (char*)d_ws;
    unsigned short* Bp    = (unsigned short*)base;
    float*          part1 = (float*)(base + 73728);
    float*          part2 = (float*)(base + 123904);
    float*          scsh1 = (float*)(base + 176128);
    unsigned short* W3p   = (unsigned short*)(base + 200704);
    float*          biasp = (float*)(base + 790528);
    unsigned short* h2t   = (unsigned short*)(base + 1048576);
    unsigned short* h1t   = (unsigned short*)d_out;            // raw conv1 out (bf16)

    dim3 blk(256);
    k_prep<<<dim3(108), blk, 0, stream>>>(w1, w21, w22, Bp);
    k_conv1<<<dim3(NBLK, NB), blk, 0, stream>>>(x, Bp, b1, h1t, part1);
    k_scsh<<<dim3(NB), dim3(128), 0, stream>>>(part1, gn1w, gn1b, scsh1);
    k_mid<<<dim3(196, NB), blk, 0, stream>>>(h1t, Bp + 18 * 512, Bp + 36 * 512,
                                             b21, b22, scsh1, h2t, part2);
    k_wprep<<<dim3(NB), blk, 0, stream>>>(w3, b3, part2, gn2w, gn2b, W3p, biasp);
    k_out<<<dim3(NBLK, NB), blk, 0, stream>>>(h2t, W3p, biasp, (float*)d_out);
}

// Round 17
// 172.177 us; speedup vs baseline: 1.0422x; 1.0422x over previous
//
#include <hip/hip_runtime.h>
#include <math.h>

#define CCH 96
#define HH 112
#define WW 112
#define HWSZ 12544      // 112*112
#define NB 32
#define PIX 64
#define NBLK 196        // tiles per image (14x14 for k_mid, 1D-64 for others)
#define EPSV 1e-5f
#define APITCH 120      // bf16 elems per A-row in conv1 staging LDS
#define TP2 104         // u16 pitch of [pixel][channel] transpose buffer (52 dw, 2-way)
#define TPITCHF 68      // f32 transpose pitch in k_out
#define ROWC 96         // channels per pixel-major row
#define HPITCH 104      // bf16 elems per halo row in k_mid LDS

typedef __attribute__((ext_vector_type(8))) short bf16x8;
typedef __attribute__((ext_vector_type(4))) float f32x4;
typedef __attribute__((ext_vector_type(8))) unsigned short u16x8;

__device__ __forceinline__ unsigned short f2bf(float f) {
    union { float f; unsigned u; } v; v.f = f;
    unsigned r = v.u + 0x7fffu + ((v.u >> 16) & 1u);   // RTNE
    return (unsigned short)(r >> 16);
}
__device__ __forceinline__ float bf2f(unsigned short h) {
    union { unsigned u; float f; } v; v.u = ((unsigned)h) << 16;
    return v.f;
}
__device__ __forceinline__ unsigned cvt_pk_bf16(float lo, float hi) {
    unsigned r;
    asm("v_cvt_pk_bf16_f32 %0, %1, %2" : "=v"(r) : "v"(lo), "v"(hi));
    return r;
}
// tanh-form GELU via hw exp2/rcp (validated rounds 5-14)
__device__ __forceinline__ float gelu_f(float x) {
    const float K = 2.3022082f;
    float u = x * x;
    float p = x * fmaf(0.044715f, u, 1.0f);
    float e = __builtin_amdgcn_exp2f(p * K);
    float r = __builtin_amdgcn_rcpf(e + 1.0f);
    return x - x * r;
}

__device__ __forceinline__ void block_reduce_write(float sum, float sumsq,
                                                   float* part, int slot) {
    #pragma unroll
    for (int off = 32; off > 0; off >>= 1) {
        sum += __shfl_down(sum, off);
        sumsq += __shfl_down(sumsq, off);
    }
    __shared__ float ls[8];
    const int wid = threadIdx.x >> 6, lane = threadIdx.x & 63;
    if (lane == 0) { ls[wid] = sum; ls[4 + wid] = sumsq; }
    __syncthreads();
    if (threadIdx.x == 0) {
        part[slot * 2 + 0] = ls[0] + ls[1] + ls[2] + ls[3];
        part[slot * 2 + 1] = ls[4] + ls[5] + ls[6] + ls[7];
    }
}

// wave-0 reduce of one sample's 196 partial pairs -> (mu, inv) in shared
__device__ __forceinline__ void stats_reduce(const float* __restrict__ part,
                                             int b, float* sh_mu, float* sh_inv) {
    const int t = threadIdx.x;
    if (t < 64) {
        float s = 0.f, q = 0.f;
        for (int i = t; i < NBLK; i += 64) {
            s += part[(b * NBLK + i) * 2 + 0];
            q += part[(b * NBLK + i) * 2 + 1];
        }
        #pragma unroll
        for (int off = 32; off > 0; off >>= 1) {
            s += __shfl_down(s, off);
            q += __shfl_down(q, off);
        }
        if (t == 0) {
            const float n = (float)CCH * (float)HWSZ;
            const float mu = s / n;
            const float var = q / n - mu * mu;
            *sh_mu = mu;
            *sh_inv = rsqrtf(var + EPSV);
        }
    }
}

// write one C-fragment column (4 pixels x 1 ch) into [pixel][ch] LDS, conflict-free
__device__ __forceinline__ void frag_to_lds_t(unsigned short* Tsd2, int p0, int o,
                                              const f32x4 v) {
    const unsigned lo = cvt_pk_bf16(v[0], v[1]);
    const unsigned hi = cvt_pk_bf16(v[2], v[3]);
    Tsd2[(p0 + 0) * TP2 + o] = (unsigned short)lo;
    Tsd2[(p0 + 1) * TP2 + o] = (unsigned short)(lo >> 16);
    Tsd2[(p0 + 2) * TP2 + o] = (unsigned short)hi;
    Tsd2[(p0 + 3) * TP2 + o] = (unsigned short)(hi >> 16);
}

// ---- weight prep: fp32 [O][C] -> bf16 fragment layout [m][n0][k0][lane][8] ----
__global__ void k_prep(const float* __restrict__ w1, const float* __restrict__ w21,
                       const float* __restrict__ w22,
                       unsigned short* __restrict__ Bp) {
    const int t = blockIdx.x * 256 + threadIdx.x;   // 3*18*512 = 27648
    if (t >= 3 * 18 * 512) return;
    const int j  = t & 7;
    const int l  = (t >> 3) & 63;
    const int s  = t >> 9;
    const int k0 = s % 3;
    const int n0 = (s / 3) % 6;
    const int m  = s / 18;
    const float* w = (m == 0) ? w1 : (m == 1) ? w21 : w22;
    const int n = n0 * 16 + (l & 15);
    const int k = k0 * 32 + (l >> 4) * 8 + j;
    Bp[t] = f2bf(w[n * CCH + k]);
}

// ---- K1: conv1 (x fp32 channel-major -> h1 bf16 PIXEL-major) + GN1 partials
__global__ __launch_bounds__(256) void k_conv1(
        const float* __restrict__ x, const unsigned short* __restrict__ Bp,
        const float* __restrict__ b1, unsigned short* __restrict__ h1t,
        float* __restrict__ part) {
    __shared__ unsigned short smem[64 * APITCH];   // 15360 B; Tsd2 (13312 B) reuses
    unsigned short* Asd = smem;
    unsigned short* Tsd2 = smem;

    const int b = blockIdx.y;
    const int hw0 = blockIdx.x * PIX;
    const int wid = __builtin_amdgcn_readfirstlane(threadIdx.x >> 6);
    const int lane = threadIdx.x & 63;

    const float* xb = x + (size_t)b * CCH * HWSZ + hw0;
    #pragma unroll
    for (int i = 0; i < 24; i += 2) {
        const int c = wid * 24 + i;
        *(unsigned*)&Asd[lane * APITCH + c] =
            cvt_pk_bf16(xb[(size_t)c * HWSZ + lane], xb[(size_t)(c + 1) * HWSZ + lane]);
    }
    __syncthreads();

    bf16x8 a[3];
    const int arow = (wid * 16 + (lane & 15)) * APITCH;
    const int acol = (lane >> 4) * 8;
    #pragma unroll
    for (int k0 = 0; k0 < 3; ++k0)
        a[k0] = *(const bf16x8*)&Asd[arow + k0 * 32 + acol];
    __syncthreads();

    f32x4 acc[6];
    #pragma unroll
    for (int n0 = 0; n0 < 6; ++n0) {
        const float bias = b1[n0 * 16 + (lane & 15)];
        acc[n0] = (f32x4){bias, bias, bias, bias};
        #pragma unroll
        for (int k0 = 0; k0 < 3; ++k0) {
            const bf16x8 bf = *(const bf16x8*)(Bp + (n0 * 3 + k0) * 512 + lane * 8);
            acc[n0] = __builtin_amdgcn_mfma_f32_16x16x32_bf16(a[k0], bf, acc[n0], 0, 0, 0);
        }
    }

    float sum = 0.f, sumsq = 0.f;
    const int p0 = wid * 16 + (lane >> 4) * 4;
    #pragma unroll
    for (int n0 = 0; n0 < 6; ++n0) {
        const int o = n0 * 16 + (lane & 15);
        #pragma unroll
        for (int r = 0; r < 4; ++r) {
            const float v = acc[n0][r];
            sum += v; sumsq += v * v;
        }
        frag_to_lds_t(Tsd2, p0, o, acc[n0]);
    }
    __syncthreads();

    // cooperative PIXEL-major store (incremental div/mod: step 256 = 21*12 + 4)
    unsigned short* ob = h1t + ((size_t)b * HWSZ + hw0) * ROWC;
    {
        int pr = threadIdx.x / 12;
        int cc = threadIdx.x % 12;
        #pragma unroll
        for (int it = 0; it < 3; ++it) {
            const int c16 = cc * 8;
            *(uint4*)&ob[(size_t)pr * ROWC + c16] = *(const uint4*)&Tsd2[pr * TP2 + c16];
            pr += 21; cc += 4;
            if (cc >= 12) { cc -= 12; pr += 1; }
        }
    }
    block_reduce_write(sum, sumsq, part, b * NBLK + blockIdx.x);
}

// ---- K2: GN1 stats -> per-(b,c) scale/shift table (scale[c], shift[96+c]) ----
__global__ void k_scsh(const float* __restrict__ part,
                       const float* __restrict__ gw, const float* __restrict__ gb,
                       float* __restrict__ scsh) {
    const int b = blockIdx.x;
    __shared__ float sh_mu, sh_inv;
    stats_reduce(part, b, &sh_mu, &sh_inv);
    __syncthreads();
    const int t = threadIdx.x;   // 128
    if (t < CCH) {
        const float sc = sh_inv * gw[t];
        scsh[b * 2 * CCH + t] = sc;
        scsh[b * 2 * CCH + CCH + t] = gb[t] - sh_mu * sc;
    }
}

// ---- K3: fused gn1+gelu (halo-staged, T14 async-split, scsh-precomputed)
//      -> 2 GEMMs -> gelu+add -> h2t + GN2 partials. 8x8 tile, 10x10 halo.
__global__ __launch_bounds__(256) void k_mid(
        const unsigned short* __restrict__ h1t,
        const unsigned short* __restrict__ BpA, const unsigned short* __restrict__ BpB,
        const float* __restrict__ b21, const float* __restrict__ b22,
        const float* __restrict__ scsh,
        unsigned short* __restrict__ h2t, float* __restrict__ part2) {
    __shared__ unsigned short Hs[100 * HPITCH];    // 20800 B; Tsd2 (13312 B) reuses
    unsigned short* Tsd2 = Hs;

    const int b = blockIdx.y;
    const int oy = (blockIdx.x / 14) * 8;          // tile origin
    const int ox = (blockIdx.x % 14) * 8;
    const int tid = threadIdx.x;

    // ---- T14 phase A: ISSUE halo global loads FIRST; latency overlaps the
    // scsh table loads below.
    const unsigned short* hb1 = h1t + (size_t)b * HWSZ * ROWC;
    u16x8 gv0, gv1, gv2, gv3, gv4;
    bool ok0 = false, ok1 = false, ok2 = false, ok3 = false, ok4 = false;
    int lr0 = 0, c0 = 0;
    if (tid < 240) {
        lr0 = tid / 12;                        // 0..19 (row within 20-row band)
        c0  = (tid % 12) * 8;                  // channel start
        const int a0  = (lr0 >= 10) ? 1 : 0;
        const int b0  = lr0 - 10 * a0;
        const int wwg = ox - 1 + b0;           // global col (iteration-invariant)
        const bool okw = (unsigned)wwg < WW;
        const int hh0 = oy - 1 + a0;
#define LOAD_IT(K, gvK, okK)                                                    \
        {                                                                       \
            const int hh = hh0 + 2 * (K);                                       \
            okK = okw && (unsigned)hh < HH;                                     \
            const size_t off = okK ? (((size_t)hh * WW + wwg) * ROWC + c0) : 0; \
            gvK = *(const u16x8*)&hb1[off];                                     \
        }
        LOAD_IT(0, gv0, ok0)
        LOAD_IT(1, gv1, ok1)
        LOAD_IT(2, gv2, ok2)
        LOAD_IT(3, gv3, ok3)
        LOAD_IT(4, gv4, ok4)
#undef LOAD_IT
    }

    // ---- phase B/C: load scale/shift (L2-resident) and gn1+gelu -> Hs
    if (tid < 240) {
        const float* scb = scsh + b * 2 * CCH;
        const f32x4 s0 = *(const f32x4*)&scb[c0];
        const f32x4 s1 = *(const f32x4*)&scb[c0 + 4];
        const f32x4 t0 = *(const f32x4*)&scb[CCH + c0];
        const f32x4 t1 = *(const f32x4*)&scb[CCH + c0 + 4];
#define PROC_IT(K, gvK, okK)                                                    \
        {                                                                       \
            unsigned r0 = 0, r1 = 0, r2 = 0, r3 = 0;                            \
            if (okK) {                                                          \
                float f0 = gelu_f(fmaf(bf2f(gvK[0]), s0[0], t0[0]));            \
                float f1 = gelu_f(fmaf(bf2f(gvK[1]), s0[1], t0[1]));            \
                float f2 = gelu_f(fmaf(bf2f(gvK[2]), s0[2], t0[2]));            \
                float f3 = gelu_f(fmaf(bf2f(gvK[3]), s0[3], t0[3]));            \
                float f4 = gelu_f(fmaf(bf2f(gvK[4]), s1[0], t1[0]));            \
                float f5 = gelu_f(fmaf(bf2f(gvK[5]), s1[1], t1[1]));            \
                float f6 = gelu_f(fmaf(bf2f(gvK[6]), s1[2], t1[2]));            \
                float f7 = gelu_f(fmaf(bf2f(gvK[7]), s1[3], t1[3]));            \
                r0 = cvt_pk_bf16(f0, f1);                                       \
                r1 = cvt_pk_bf16(f2, f3);                                       \
                r2 = cvt_pk_bf16(f4, f5);                                       \
                r3 = cvt_pk_bf16(f6, f7);                                       \
            }                                                                   \
            *(uint4*)&Hs[((K) * 20 + lr0) * HPITCH + c0] =                      \
                make_uint4(r0, r1, r2, r3);                                     \
        }
        PROC_IT(0, gv0, ok0)
        PROC_IT(1, gv1, ok1)
        PROC_IT(2, gv2, ok2)
        PROC_IT(3, gv3, ok3)
        PROC_IT(4, gv4, ok4)
#undef PROC_IT
    }
    __syncthreads();

    const int wid = __builtin_amdgcn_readfirstlane(tid >> 6);
    const int lane = tid & 63;
    const int p = wid * 16 + (lane & 15);          // tile-local pixel 0..63
    const int hr = ((p >> 3) + 1) * 10 + (p & 7) + 1;   // center halo row
    const int acol8 = (lane >> 4) * 8;

    // chunk k0=0: shift +1; k0=1: center; k0=2: shift -1 (all in-LDS, pre-zeroed)
    bf16x8 alr[3], atd[3];
    alr[0] = *(const bf16x8*)&Hs[(hr + 1)  * HPITCH +  0 + acol8];
    alr[1] = *(const bf16x8*)&Hs[hr        * HPITCH + 32 + acol8];
    alr[2] = *(const bf16x8*)&Hs[(hr - 1)  * HPITCH + 64 + acol8];
    atd[0] = *(const bf16x8*)&Hs[(hr + 10) * HPITCH +  0 + acol8];
    atd[1] = alr[1];
    atd[2] = *(const bf16x8*)&Hs[(hr - 10) * HPITCH + 64 + acol8];

    f32x4 accA[6], accB[6];
    #pragma unroll
    for (int n0 = 0; n0 < 6; ++n0) {
        const float biasA = b21[n0 * 16 + (lane & 15)];
        const float biasB = b22[n0 * 16 + (lane & 15)];
        accA[n0] = (f32x4){biasA, biasA, biasA, biasA};
        accB[n0] = (f32x4){biasB, biasB, biasB, biasB};
        #pragma unroll
        for (int k0 = 0; k0 < 3; ++k0) {
            const bf16x8 bA = *(const bf16x8*)(BpA + (n0 * 3 + k0) * 512 + lane * 8);
            const bf16x8 bB = *(const bf16x8*)(BpB + (n0 * 3 + k0) * 512 + lane * 8);
            accA[n0] = __builtin_amdgcn_mfma_f32_16x16x32_bf16(alr[k0], bA, accA[n0], 0, 0, 0);
            accB[n0] = __builtin_amdgcn_mfma_f32_16x16x32_bf16(atd[k0], bB, accB[n0], 0, 0, 0);
        }
    }
    __syncthreads();   // all waves done reading Hs before Tsd2 overlay

    float sum = 0.f, sumsq = 0.f;
    const int p0 = wid * 16 + (lane >> 4) * 4;
    #pragma unroll
    for (int n0 = 0; n0 < 6; ++n0) {
        const int o = n0 * 16 + (lane & 15);
        f32x4 vv;
        #pragma unroll
        for (int r = 0; r < 4; ++r) {
            const float v = gelu_f(accA[n0][r]) + gelu_f(accB[n0][r]);
            sum += v; sumsq += v * v;
            vv[r] = v;
        }
        frag_to_lds_t(Tsd2, p0, o, vv);
    }
    __syncthreads();

    unsigned short* ob = h2t + (size_t)b * HWSZ * ROWC;
    {
        int pr = tid / 12;
        int cc = tid % 12;
        #pragma unroll
        for (int it = 0; it < 3; ++it) {
            const int c16 = cc * 8;
            const size_t gp = (size_t)(oy + (pr >> 3)) * WW + ox + (pr & 7);
            *(uint4*)&ob[gp * ROWC + c16] = *(const uint4*)&Tsd2[pr * TP2 + c16];
            pr += 21; cc += 4;
            if (cc >= 12) { cc -= 12; pr += 1; }
        }
    }
    block_reduce_write(sum, sumsq, part2, b * NBLK + blockIdx.x);
}

// ---- K4: per-sample GN2 fold into conv3 (stats folded in) ----
__global__ void k_wprep(const float* __restrict__ w3, const float* __restrict__ b3,
                        const float* __restrict__ part2,
                        const float* __restrict__ gw, const float* __restrict__ gb,
                        unsigned short* __restrict__ W3p, float* __restrict__ biasp) {
    const int b = blockIdx.x;
    __shared__ float ts[CCH], th[CCH];
    __shared__ float sh_mu, sh_inv;
    stats_reduce(part2, b, &sh_mu, &sh_inv);
    __syncthreads();
    const int t = threadIdx.x;
    if (t < CCH) {
        const float sc = sh_inv * gw[t];
        ts[t] = sc;
        th[t] = gb[t] - sh_mu * sc;
    }
    __syncthreads();
    unsigned short* Wb = W3p + b * 9216;
    #pragma unroll
    for (int i = 0; i < 36; ++i) {
        const int idx = t + i * 256;               // < 9216
        const int j = idx & 7;
        const int l = (idx >> 3) & 63;
        const int s = idx >> 9;
        const int k0 = s % 3, n0 = s / 3;
        const int n = n0 * 16 + (l & 15);
        const int k = k0 * 32 + (l >> 4) * 8 + j;
        Wb[idx] = f2bf(w3[n * CCH + k] * ts[k]);
    }
    if (t < CCH) {
        float a = b3[t];
        for (int c = 0; c < CCH; ++c) a = fmaf(w3[t * CCH + c], th[c], a);
        biasp[b * CCH + t] = a;
    }
}

// ---- K5: raw frag loads from h2t -> conv3' -> out fp32 channel-major ----
__global__ __launch_bounds__(256) void k_out(
        const unsigned short* __restrict__ h2t, const unsigned short* __restrict__ W3p,
        const float* __restrict__ biasp, float* __restrict__ out) {
    __shared__ float Tf[CCH * TPITCHF];   // 26112 B

    const int b = blockIdx.y;
    const int hw0 = blockIdx.x * PIX;
    const int wid = __builtin_amdgcn_readfirstlane(threadIdx.x >> 6);
    const int lane = threadIdx.x & 63;
    const int prow = hw0 + wid * 16 + (lane & 15);
    const int acol8 = (lane >> 4) * 8;

    const unsigned short* hb = h2t + (size_t)b * HWSZ * ROWC;
    bf16x8 a[3];
    #pragma unroll
    for (int k0 = 0; k0 < 3; ++k0)
        a[k0] = *(const bf16x8*)(hb + (size_t)prow * ROWC + k0 * 32 + acol8);

    const unsigned short* Bb = W3p + b * 9216;
    f32x4 acc[6];
    #pragma unroll
    for (int n0 = 0; n0 < 6; ++n0) {
        const float bias = biasp[b * CCH + n0 * 16 + (lane & 15)];
        acc[n0] = (f32x4){bias, bias, bias, bias};
        #pragma unroll
        for (int k0 = 0; k0 < 3; ++k0) {
            const bf16x8 bf = *(const bf16x8*)(Bb + (n0 * 3 + k0) * 512 + lane * 8);
            acc[n0] = __builtin_amdgcn_mfma_f32_16x16x32_bf16(a[k0], bf, acc[n0], 0, 0, 0);
        }
    }

    const int p0 = wid * 16 + (lane >> 4) * 4;
    #pragma unroll
    for (int n0 = 0; n0 < 6; ++n0) {
        const int o = n0 * 16 + (lane & 15);
        *(f32x4*)&Tf[o * TPITCHF + p0] = acc[n0];
    }
    __syncthreads();

    float* op = out + (size_t)b * CCH * HWSZ + hw0;
    #pragma unroll
    for (int it = 0; it < 6; ++it) {
        const int o = it * 16 + (threadIdx.x >> 4);
        const int p = (threadIdx.x & 15) * 4;
        *(f32x4*)&op[(size_t)o * HWSZ + p] = *(const f32x4*)&Tf[o * TPITCHF + p];
    }
}

extern "C" void kernel_launch(void* const* d_in, const int* in_sizes, int n_in,
                              void* d_out, int out_size, void* d_ws, size_t ws_size,
                              hipStream_t stream) {
    const float* x    = (const float*)d_in[0];
    const float* w1   = (const float*)d_in[1];
    const float* b1   = (const float*)d_in[2];
    const float* w21  = (const float*)d_in[3];
    const float* b21  = (const float*)d_in[4];
    const float* w22  = (const float*)d_in[5];
    const float* b22  = (const float*)d_in[6];
    const float* w3   = (const float*)d_in[7];
    const float* b3   = (const float*)d_in[8];
    const float* gn1w = (const float*)d_in[9];
    const float* gn1b = (const float*)d_in[10];
    const float* gn2w = (const float*)d_in[11];
    const float* gn2b = (const float*)d_in[12];

    // Workspace layout — verified non-overlapping (R4 lesson):
    //   Bp    [0,       55296)
    //   part1 [73728,   123904)
    //   part2 [123904,  174080)
    //   scsh1 [176128,  200704)
    //   W3p   [200704,  790528)
    //   biasp [790528,  802816)
    //   h2t   [1048576, +77 MB)
    char* base = (char*)d_ws;
    unsigned short* Bp    = (unsigned short*)base;
    float*          part1 = (float*)(base + 73728);
    float*          part2 = (float*)(base + 123904);
    float*          scsh1 = (float*)(base + 176128);
    unsigned short* W3p   = (unsigned short*)(base + 200704);
    float*          biasp = (float*)(base + 790528);
    unsigned short* h2t   = (unsigned short*)(base + 1048576);
    unsigned short* h1t   = (unsigned short*)d_out;            // raw conv1 out (bf16)

    dim3 blk(256);
    k_prep<<<dim3(108), blk, 0, stream>>>(w1, w21, w22, Bp);
    k_conv1<<<dim3(NBLK, NB), blk, 0, stream>>>(x, Bp, b1, h1t, part1);
    k_scsh<<<dim3(NB), dim3(128), 0, stream>>>(part1, gn1w, gn1b, scsh1);
    k_mid<<<dim3(196, NB), blk, 0, stream>>>(h1t, Bp + 18 * 512, Bp + 36 * 512,
                                             b21, b22, scsh1, h2t, part2);
    k_wprep<<<dim3(NB), blk, 0, stream>>>(w3, b3, part2, gn2w, gn2b, W3p, biasp);
    k_out<<<dim3(NBLK, NB), blk, 0, stream>>>(h2t, W3p, biasp, (float*)d_out);
}